// Round 12
// baseline (1009.917 us; speedup 1.0000x reference)
//
#include <hip/hip_runtime.h>
#include <hip/hip_bf16.h>

#define TT 512
#define MCELLS 16384            // B*N = 256*64
#define LOG2E 1.44269504088896340736f
#define LN2   0.69314718055994530942f

typedef __attribute__((ext_vector_type(8))) short bf16x8;
typedef __attribute__((ext_vector_type(4))) float f32x4;
typedef __attribute__((ext_vector_type(4))) unsigned u32x4;

__device__ __forceinline__ short f2bf(float f) {
    __hip_bfloat16 h = __float2bfloat16(f);
    return __builtin_bit_cast(short, h);
}
// two f32 -> packed bf16 dword (low16 = a, high16 = b), RNE in HW
__device__ __forceinline__ unsigned cvtpk(float a, float b) {
    unsigned r;
    asm("v_cvt_pk_bf16_f32 %0, %1, %2" : "=v"(r) : "v"(a), "v"(b));
    return r;
}

// Validated tanh LUT (R10): DIRECT array indexing only. (sigma-via-LUT failed
// 3x at ~3e-2 -- R8/R9/R11 anomaly, abandoned. sigma stays on exp2.)
// tanh table: domain [-8,8], step 1/128, 2048 intervals + guard.
#define LUT_TANH(xv, dst) {                                            \
    const float _c = __builtin_amdgcn_fmed3f((xv), -8.0f, 7.9921875f); \
    const float _u = fmaf(_c, 128.0f, 1024.0f);                        \
    const int   _i = (int)_u;                                          \
    const float _f = _u - (float)_i;                                   \
    (dst) = fmaf(_f, tanD[_i], tanY[_i]); }

// Persistent LSTM, 8 waves/SIMD edition.
// grid = 1024 blocks x 512 threads (8 waves) = 4 blocks/CU = 32 waves/CU.
// Block owns 16 cells (cell = blockIdx*16 + (lane&15)). Wave w owns hdims
// [8w, 8w+8) via TWO gate-interleaved 16x16 MFMA tiles T = 2w, 2w+1:
//   tile T row rho = (gate = rho&3, hdim = 4T + (rho>>2))
// so D's lane mapping (row = 4*hi + r) gives acc[r] = gate r of
// (cell = lane&15, hdim = 4T + hi): each lane gets complete (i,f,g,o) quads
// for 2 elems -- no cross-wave gate exchange, no MFMA waste at 2 elems/lane.
// K=96: 3rd MFMA carries x*W_ih + bias (B-ext rows [x,1]). g_t = h.wg via
// 2 extra MFMAs (AWg row 0 = wg). Output round-robins over 8 waves.
__global__ __launch_bounds__(512, 8)
void lstm_net_kernel(const float* __restrict__ input,
                     const float* __restrict__ w1,
                     const float* __restrict__ b1,
                     const float* __restrict__ w2,
                     const float* __restrict__ b2,
                     const float* __restrict__ W_ih,
                     const float* __restrict__ W_hh,
                     const float* __restrict__ b_ih,
                     const float* __restrict__ b_hh,
                     const float* __restrict__ wg,
                     const float* __restrict__ bg,
                     float* __restrict__ out)
{
    __shared__ float tanY[2049];
    __shared__ float tanD[2049];
    // h double buffer: 2 x 16 rows(cells) x 144B (64 bf16 + pad)
    __shared__ __align__(16) char hbuf[2 * 16 * 144];

    const int tid  = threadIdx.x;
    const int wv   = tid >> 6;          // 0..7: 8-hdim slice
    const int lane = tid & 63;
    const int lo   = lane & 15;
    const int hi   = lane >> 4;

    // ---- build tanh table (one-time): tanh on [-8, 8], step 1/128 ----
    for (int idx = tid; idx < 2049; idx += 512) {
        const float xv = (float)idx * 0.0078125f - 8.0f;
        const float e0 = __builtin_amdgcn_exp2f(2.0f * LOG2E * xv);
        const float e1 = __builtin_amdgcn_exp2f(2.0f * LOG2E * (xv + 0.0078125f));
        const float t0 = 1.0f - 2.0f / (1.0f + e0);
        const float t1 = 1.0f - 2.0f / (1.0f + e1);
        tanY[idx] = t0;
        tanD[idx] = t1 - t0;
    }

    for (int o = tid; o < (2 * 16 * 144) / 4; o += 512)
        ((unsigned*)hbuf)[o] = 0u;      // h0 = 0 (both buffers)

    // ---- per-cell constants ----
    const int cell = blockIdx.x * 16 + lo;
    const int n    = cell & 63;
    float a_n = 0.f, c_n = 0.f;
    #pragma unroll
    for (int k = 0; k < 10; ++k) {
        a_n += w1[n * 10 + k] * w2[n * 10 + k];   // per-neuron affine collapse
        c_n += b1[n * 10 + k] * w2[n * 10 + k];
    }
    c_n += b2[n];
    const float bgv = bg[0];

    // ---- A-fragments (gate-interleaved tiles), VGPR-resident ----
    // tile t2: T = 2*wv + t2; within-tile row rho = lo:
    //   Wrow = (lo&3)*64 + 4*T + (lo>>2)
    bf16x8 AWf[2][3];
    #pragma unroll
    for (int t2 = 0; t2 < 2; ++t2) {
        const int T    = 2 * wv + t2;
        const int Wrow = (lo & 3) * 64 + 4 * T + (lo >> 2);
        #pragma unroll
        for (int kk = 0; kk < 2; ++kk) {
            const float* src = W_hh + Wrow * 64 + kk * 32 + hi * 8;
            bf16x8 v;
            #pragma unroll
            for (int e = 0; e < 8; ++e) v[e] = f2bf(src[e]);
            AWf[t2][kk] = v;
        }
        bf16x8 vx = {};                 // K-ext: col64 = W_ih, col65 = bias
        if (hi == 0) {
            vx[0] = f2bf(W_ih[Wrow]);
            vx[1] = f2bf(b_ih[Wrow] + b_hh[Wrow]);
        }
        AWf[t2][2] = vx;
    }
    // g-dot A-frags: row 0 = wg (lanes lo==0), rows 1..15 = 0
    bf16x8 AWg[2];
    #pragma unroll
    for (int kk = 0; kk < 2; ++kk) {
        bf16x8 v = {};
        if (lo == 0) {
            const float* src = wg + kk * 32 + hi * 8;
            #pragma unroll
            for (int e = 0; e < 8; ++e) v[e] = f2bf(src[e]);
        }
        AWg[kk] = v;
    }

    const f32x4 zero4 = {0.f, 0.f, 0.f, 0.f};
    float cst[2] = {0.f, 0.f};          // c state for the lane's 2 elems
    float sp0 = 0.f;                    // softplus at t=0 (held by wave 1)
    float gA  = 0.f;                    // accg[0] from previous iter
    const float* inP  = input + cell;
    float*       outP = out + cell;
    float raw_next = inP[0];

    __syncthreads();                    // table + h0 visible

    for (int t = 0; t < TT; ++t) {
        const float raw = raw_next;
        raw_next = inP[((t + 1) & (TT - 1)) * MCELLS];
        const float x = raw * a_n + c_n;            // outLin[t,cell]

        // B-ext frag: rows 64..95 of B = [x, 1, 0...] (per cell = lo)
        u32x4 bxi = {0u, 0u, 0u, 0u};
        bxi[0] = (hi == 0) ? cvtpk(x, 1.0f) : 0u;
        const bf16x8 bx = __builtin_bit_cast(bf16x8, bxi);

        // h B-frags: cell = lo, hdims hi*8.. / 32+hi*8..  (full h, K=64)
        const char* hrd = hbuf + (t & 1) * 2304 + lo * 144;
        const bf16x8 bf0 = *(const bf16x8*)(hrd + hi * 16);
        const bf16x8 bf1 = *(const bf16x8*)(hrd + 64 + hi * 16);

        f32x4 acc[2];
        #pragma unroll
        for (int t2 = 0; t2 < 2; ++t2) {
            acc[t2] = __builtin_amdgcn_mfma_f32_16x16x32_bf16(AWf[t2][2], bx,  zero4,  0, 0, 0);
            acc[t2] = __builtin_amdgcn_mfma_f32_16x16x32_bf16(AWf[t2][0], bf0, acc[t2], 0, 0, 0);
            acc[t2] = __builtin_amdgcn_mfma_f32_16x16x32_bf16(AWf[t2][1], bf1, acc[t2], 0, 0, 0);
        }
        // g = wg . h_t  (row 0 -> lanes hi==0, reg 0)
        f32x4 accg;
        accg = __builtin_amdgcn_mfma_f32_16x16x32_bf16(AWg[0], bf0, zero4, 0, 0, 0);
        accg = __builtin_amdgcn_mfma_f32_16x16x32_bf16(AWg[1], bf1, accg, 0, 0, 0);

        // activations (R10-validated math): elem t2 = (cell=lo, hdim=8wv+4t2+hi)
        // acc[t2][r] = gate r: 0=i, 1=f, 2=g, 3=o
        char* hw = hbuf + ((t + 1) & 1) * 2304 + lo * 144;
        #pragma unroll
        for (int t2 = 0; t2 < 2; ++t2) {
            const float ip = acc[t2][0];
            const float fp = acc[t2][1];
            const float gp = acc[t2][2];
            const float op = acc[t2][3];

            const float Ei = __builtin_amdgcn_exp2f(-LOG2E * ip);
            const float Ef = __builtin_amdgcn_exp2f(-LOG2E * fp);
            const float Eo = __builtin_amdgcn_exp2f(-LOG2E * op);

            float tg;
            LUT_TANH(gp, tg);

            // cp = c*sig(f) + tg*sig(i) = [c*(1+Ei) + tg*(1+Ef)]*rcp((1+Ei)(1+Ef))
            const float A1 = 1.f + Ei;
            const float A2 = 1.f + Ef;
            const float cp = (cst[t2] * A1 + tg * A2) *
                             __builtin_amdgcn_rcpf(A1 * A2);
            cst[t2] = cp;

            float tc;
            LUT_TANH(cp, tc);
            const float hv = tc * __builtin_amdgcn_rcpf(1.f + Eo);

            // h-write: bf16 at hdim d = 8*wv + 4*t2 + hi
            *(short*)(hw + 2 * (8 * wv + 4 * t2 + hi)) = f2bf(hv);
        }

        // output: out[t] = g_prev[t]*softplus(x-1); g_prev = {g_0, 1, g_{t-2}..}
        // round-robin: wave (t&7) handles step t (t=0 handled by wave 1).
        if (((t == 0) ? (wv == 1) : ((t & 7) == wv)) && hi == 0) {
            const float spE = __builtin_amdgcn_exp2f(LOG2E * (x - 1.f));
            const float sp  = LN2 * __builtin_amdgcn_logf(1.f + spE);
            if (t == 0) {
                sp0 = sp;                               // wave 1 holds sp_0
            } else if (t == 1) {
                outP[MCELLS] = sp;                      // g_prev[1] = 1
                outP[0] = (accg[0] + bgv) * sp0;        // g_0 * sp_0 (fresh accg)
            } else {
                outP[t * MCELLS] = (gA + bgv) * sp;     // g_{t-2} * sp_t
            }
        }
        gA = accg[0];                   // delay register: g_{t-1} for next iter
        __syncthreads();                // h(t+1) visible to all waves
    }
}

extern "C" void kernel_launch(void* const* d_in, const int* in_sizes, int n_in,
                              void* d_out, int out_size, void* d_ws, size_t ws_size,
                              hipStream_t stream) {
    const float* input = (const float*)d_in[0];
    const float* w1    = (const float*)d_in[1];
    const float* b1    = (const float*)d_in[2];
    const float* w2    = (const float*)d_in[3];
    const float* b2    = (const float*)d_in[4];
    const float* W_ih  = (const float*)d_in[5];
    const float* W_hh  = (const float*)d_in[6];
    const float* b_ih  = (const float*)d_in[7];
    const float* b_hh  = (const float*)d_in[8];
    const float* wg    = (const float*)d_in[9];
    const float* bg    = (const float*)d_in[10];

    lstm_net_kernel<<<dim3(1024), dim3(512), 0, stream>>>(
        input, w1, b1, w2, b2, W_ih, W_hh, b_ih, b_hh, wg, bg, (float*)d_out);
}

// Round 13
// 804.859 us; speedup vs baseline: 1.2548x; 1.2548x over previous
//
#include <hip/hip_runtime.h>
#include <hip/hip_bf16.h>

#define TT 512
#define MCELLS 16384            // B*N = 256*64
#define LOG2E 1.44269504088896340736f
#define LN2   0.69314718055994530942f

typedef __attribute__((ext_vector_type(8))) short bf16x8;
typedef __attribute__((ext_vector_type(4))) float f32x4;

__device__ __forceinline__ short f2bf(float f) {
    __hip_bfloat16 h = __float2bfloat16(f);
    return __builtin_bit_cast(short, h);
}

// Validated tanh LUT (R10): DIRECT array indexing only. (sigma-via-LUT failed
// 3x at ~3e-2 -- R8/R9/R11 anomaly, abandoned. sigma stays on exp2.)
// tanh table: domain [-8,8], step 1/128, 2048 intervals + guard.
#define LUT_TANH(xv, dst) {                                            \
    const float _c = __builtin_amdgcn_fmed3f((xv), -8.0f, 7.9921875f); \
    const float _u = fmaf(_c, 128.0f, 1024.0f);                        \
    const int   _i = (int)_u;                                          \
    const float _f = _u - (float)_i;                                   \
    (dst) = fmaf(_f, tanD[_i], tanY[_i]); }

// Persistent LSTM, 8 waves/SIMD, register-dieted (R12 spilled at VGPR 32+sc).
// grid = 1024 blocks x 512 threads (8 waves) = 4 blocks/CU = 32 waves/CU.
// Block owns 16 cells (cell = blockIdx*16 + (lane&15)). Wave w owns hdims
// [8w, 8w+8) via TWO gate-interleaved 16x16 MFMA tiles T = 2w, 2w+1:
//   tile T row rho = (gate = rho&3, hdim = 4T + (rho>>2))
// so D's lane mapping gives acc[t2][r] = gate r of (cell=lane&15, hdim=4T+hi):
// complete (i,f,g,o) quads, 2 elems/lane. K=64 now: the old bias-MFMA is
// replaced by an f32 acc-init from the broadcast LDS table wib (cuts 8 regs +
// bx; more precise). g_t = h.wg via 2 extra MFMAs (AWg row 0 = wg).
// Output round-robins over 8 waves.
__global__ __launch_bounds__(512, 8)
void lstm_net_kernel(const float* __restrict__ input,
                     const float* __restrict__ w1,
                     const float* __restrict__ b1,
                     const float* __restrict__ w2,
                     const float* __restrict__ b2,
                     const float* __restrict__ W_ih,
                     const float* __restrict__ W_hh,
                     const float* __restrict__ b_ih,
                     const float* __restrict__ b_hh,
                     const float* __restrict__ wg,
                     const float* __restrict__ bg,
                     float* __restrict__ out)
{
    __shared__ float tanY[2049];
    __shared__ float tanD[2049];
    // (W_ih, b_ih+b_hh) pairs indexed [T][hi][r] -> per-wave reads broadcast
    __shared__ __align__(16) float2 wib[256];
    // h double buffer: 2 x 16 rows(cells) x 144B (64 bf16 + pad)
    __shared__ __align__(16) char hbuf[2 * 16 * 144];

    const int tid  = threadIdx.x;
    const int wv   = tid >> 6;          // 0..7: 8-hdim slice
    const int lane = tid & 63;
    const int lo   = lane & 15;
    const int hi   = lane >> 4;

    // ---- build tanh table (one-time): tanh on [-8, 8], step 1/128 ----
    for (int idx = tid; idx < 2049; idx += 512) {
        const float xv = (float)idx * 0.0078125f - 8.0f;
        const float e0 = __builtin_amdgcn_exp2f(2.0f * LOG2E * xv);
        const float e1 = __builtin_amdgcn_exp2f(2.0f * LOG2E * (xv + 0.0078125f));
        const float t0 = 1.0f - 2.0f / (1.0f + e0);
        const float t1 = 1.0f - 2.0f / (1.0f + e1);
        tanY[idx] = t0;
        tanD[idx] = t1 - t0;
    }
    // ---- wib table: (W_ih[row], b_ih[row]+b_hh[row]), row = r*64 + 4T + h4 ----
    if (tid < 256) {
        const int T  = tid >> 4;
        const int h4 = (tid >> 2) & 3;
        const int r  = tid & 3;
        const int Wrow = r * 64 + 4 * T + h4;
        wib[tid] = make_float2(W_ih[Wrow], b_ih[Wrow] + b_hh[Wrow]);
    }

    for (int o = tid; o < (2 * 16 * 144) / 4; o += 512)
        ((unsigned*)hbuf)[o] = 0u;      // h0 = 0 (both buffers)

    // ---- per-cell constants ----
    const int cell = blockIdx.x * 16 + lo;
    const int n    = cell & 63;
    float a_n = 0.f, c_n = 0.f;
    #pragma unroll
    for (int k = 0; k < 10; ++k) {
        a_n += w1[n * 10 + k] * w2[n * 10 + k];   // per-neuron affine collapse
        c_n += b1[n * 10 + k] * w2[n * 10 + k];
    }
    c_n += b2[n];
    const float bgv = bg[0];

    // ---- A-fragments (gate-interleaved tiles), K=64, VGPR-resident ----
    // tile t2: T = 2*wv + t2; within-tile row rho = lo:
    //   Wrow = (lo&3)*64 + 4*T + (lo>>2)
    bf16x8 AWf[2][2];
    #pragma unroll
    for (int t2 = 0; t2 < 2; ++t2) {
        const int T    = 2 * wv + t2;
        const int Wrow = (lo & 3) * 64 + 4 * T + (lo >> 2);
        #pragma unroll
        for (int kk = 0; kk < 2; ++kk) {
            const float* src = W_hh + Wrow * 64 + kk * 32 + hi * 8;
            bf16x8 v;
            #pragma unroll
            for (int e = 0; e < 8; ++e) v[e] = f2bf(src[e]);
            AWf[t2][kk] = v;
        }
    }
    // g-dot A-frags: row 0 = wg (lanes lo==0), rows 1..15 = 0
    bf16x8 AWg[2];
    #pragma unroll
    for (int kk = 0; kk < 2; ++kk) {
        bf16x8 v = {};
        if (lo == 0) {
            const float* src = wg + kk * 32 + hi * 8;
            #pragma unroll
            for (int e = 0; e < 8; ++e) v[e] = f2bf(src[e]);
        }
        AWg[kk] = v;
    }

    const f32x4 zero4 = {0.f, 0.f, 0.f, 0.f};
    float cst[2] = {0.f, 0.f};          // c state for the lane's 2 elems
    float sp0 = 0.f;                    // softplus at t=0 (held by wave 1)
    float gA  = 0.f;                    // accg[0] from previous iter
    const float* inP  = input + cell;
    float*       outP = out + cell;
    float raw_next = inP[0];

    __syncthreads();                    // tables + h0 visible

    for (int t = 0; t < TT; ++t) {
        const float raw = raw_next;
        raw_next = inP[((t + 1) & (TT - 1)) * MCELLS];
        const float x = raw * a_n + c_n;            // outLin[t,cell]

        // h B-frags: cell = lo, hdims hi*8.. / 32+hi*8..  (full h, K=64)
        const char* hrd = hbuf + (t & 1) * 2304 + lo * 144;
        const bf16x8 bf0 = *(const bf16x8*)(hrd + hi * 16);
        const bf16x8 bf1 = *(const bf16x8*)(hrd + 64 + hi * 16);

        f32x4 acc[2];
        #pragma unroll
        for (int t2 = 0; t2 < 2; ++t2) {
            // f32 acc init: gate r of (cell, hdim 4T+hi) = x*W_ih + bias
            const int base = (2 * wv + t2) * 16 + hi * 4;   // float2 index
            const f32x4 p01 = *(const f32x4*)&wib[base];     // (w0,b0,w1,b1)
            const f32x4 p23 = *(const f32x4*)&wib[base + 2]; // (w2,b2,w3,b3)
            f32x4 ai;
            ai[0] = fmaf(x, p01[0], p01[1]);
            ai[1] = fmaf(x, p01[2], p01[3]);
            ai[2] = fmaf(x, p23[0], p23[1]);
            ai[3] = fmaf(x, p23[2], p23[3]);
            ai = __builtin_amdgcn_mfma_f32_16x16x32_bf16(AWf[t2][0], bf0, ai, 0, 0, 0);
            acc[t2] = __builtin_amdgcn_mfma_f32_16x16x32_bf16(AWf[t2][1], bf1, ai, 0, 0, 0);
        }
        // g = wg . h_t  (row 0 -> lanes hi==0, reg 0)
        f32x4 accg;
        accg = __builtin_amdgcn_mfma_f32_16x16x32_bf16(AWg[0], bf0, zero4, 0, 0, 0);
        accg = __builtin_amdgcn_mfma_f32_16x16x32_bf16(AWg[1], bf1, accg, 0, 0, 0);

        // activations (validated math): elem t2 = (cell=lo, hdim=8wv+4t2+hi)
        // acc[t2][r] = gate r: 0=i, 1=f, 2=g, 3=o
        char* hw = hbuf + ((t + 1) & 1) * 2304 + lo * 144;
        #pragma unroll
        for (int t2 = 0; t2 < 2; ++t2) {
            const float ip = acc[t2][0];
            const float fp = acc[t2][1];
            const float gp = acc[t2][2];
            const float op = acc[t2][3];

            const float Ei = __builtin_amdgcn_exp2f(-LOG2E * ip);
            const float Ef = __builtin_amdgcn_exp2f(-LOG2E * fp);
            const float Eo = __builtin_amdgcn_exp2f(-LOG2E * op);

            float tg;
            LUT_TANH(gp, tg);

            // cp = c*sig(f) + tg*sig(i) = [c*(1+Ei) + tg*(1+Ef)]*rcp((1+Ei)(1+Ef))
            const float A1 = 1.f + Ei;
            const float A2 = 1.f + Ef;
            const float cp = (cst[t2] * A1 + tg * A2) *
                             __builtin_amdgcn_rcpf(A1 * A2);
            cst[t2] = cp;

            float tc;
            LUT_TANH(cp, tc);
            const float hv = tc * __builtin_amdgcn_rcpf(1.f + Eo);

            // h-write: bf16 at hdim d = 8*wv + 4*t2 + hi
            *(short*)(hw + 2 * (8 * wv + 4 * t2 + hi)) = f2bf(hv);
        }

        // output: out[t] = g_prev[t]*softplus(x-1); g_prev = {g_0, 1, g_{t-2}..}
        // round-robin: wave (t&7) handles step t (t=0 handled by wave 1).
        if (((t == 0) ? (wv == 1) : ((t & 7) == wv)) && hi == 0) {
            const float spE = __builtin_amdgcn_exp2f(LOG2E * (x - 1.f));
            const float sp  = LN2 * __builtin_amdgcn_logf(1.f + spE);
            if (t == 0) {
                sp0 = sp;                               // wave 1 holds sp_0
            } else if (t == 1) {
                outP[MCELLS] = sp;                      // g_prev[1] = 1
                outP[0] = (accg[0] + bgv) * sp0;        // g_0 * sp_0 (fresh accg)
            } else {
                outP[t * MCELLS] = (gA + bgv) * sp;     // g_{t-2} * sp_t
            }
        }
        gA = accg[0];                   // delay register: g_{t-1} for next iter
        __syncthreads();                // h(t+1) visible to all waves
    }
}

extern "C" void kernel_launch(void* const* d_in, const int* in_sizes, int n_in,
                              void* d_out, int out_size, void* d_ws, size_t ws_size,
                              hipStream_t stream) {
    const float* input = (const float*)d_in[0];
    const float* w1    = (const float*)d_in[1];
    const float* b1    = (const float*)d_in[2];
    const float* w2    = (const float*)d_in[3];
    const float* b2    = (const float*)d_in[4];
    const float* W_ih  = (const float*)d_in[5];
    const float* W_hh  = (const float*)d_in[6];
    const float* b_ih  = (const float*)d_in[7];
    const float* b_hh  = (const float*)d_in[8];
    const float* wg    = (const float*)d_in[9];
    const float* bg    = (const float*)d_in[10];

    lstm_net_kernel<<<dim3(1024), dim3(512), 0, stream>>>(
        input, w1, b1, w2, b2, W_ih, W_hh, b_ih, b_hh, wg, bg, (float*)d_out);
}